// Round 1
// baseline (30147.824 us; speedup 1.0000x reference)
//
#include <hip/hip_runtime.h>
#include <hip/hip_bf16.h>

#define DI __device__ __forceinline__
#define GRIDN 256

typedef short short8 __attribute__((ext_vector_type(8)));
typedef short short4_ __attribute__((ext_vector_type(4)));
typedef float float4_ __attribute__((ext_vector_type(4)));

DI float4_ mfma16(short8 a, short8 b, float4_ c){
  return __builtin_amdgcn_mfma_f32_16x16x32_bf16(a, b, c, 0, 0, 0);
}
DI short f2b(float x){
  unsigned u = __builtin_bit_cast(unsigned, x);
  u += 0x7fffu + ((u>>16)&1u);
  return (short)(u>>16);
}
DI float b2f(short x){
  unsigned u = ((unsigned)(unsigned short)x)<<16;
  return __builtin_bit_cast(float, u);
}
DI float elu_(float x){ return x>0.f ? x : (__expf(x)-1.f); }
DI float sigm_(float x){ return 1.f/(1.f+__expf(-x)); }
DI float tanh_(float x){ float e=__expf(2.f*x); return 1.f-2.f/(e+1.f); }

DI short8 ldA(const short* base, int ld, int row0, int k0, int lane){
  return *(const short8*)(base + (size_t)(row0 + (lane&15))*ld + k0 + ((lane>>4)<<3));
}
DI short8 ldB(const short* swz, int nf, int kf, int KF, int lane){
  return *(const short8*)(swz + (((size_t)nf*KF + kf)<<9) + (lane<<3));
}

// ---------------- init: zero ctrl + h ----------------
__global__ void k_init(unsigned* ctrl, float* hfrag, short* hbf){
  size_t i = (size_t)blockIdx.x*blockDim.x + threadIdx.x;
  if (i < 1024) ctrl[i] = 0u;
  if (i < 524288){ hfrag[i] = 0.f; hbf[i] = 0; }
}

// ---------------- weight swizzle: row-major f32 (N,K) -> frag layout ----------------
__global__ void k_swz(const float* __restrict__ src, short* __restrict__ dst,
                      int stride, int coloff, int nfoff, int KF){
  const int kf = blockIdx.x, nf = blockIdx.y, l = threadIdx.x;
  const float* p = src + (size_t)((nf<<4) + (l&15))*stride + coloff + (kf<<5) + ((l>>4)<<3);
  short8 v;
  #pragma unroll
  for (int e=0;e<8;e++) v[e]=f2b(p[e]);
  *(short8*)(dst + (((size_t)(nfoff+nf)*KF + kf)<<9) + (l<<3)) = v;
}

// ---------------- Wce = posW0e @ encW2 (f32, small) ----------------
__global__ void k_wce(const float* __restrict__ posW0, const float* __restrict__ encW2,
                      float* __restrict__ wce){
  __shared__ float As[16][17], Bs[16][17];
  const int tx = threadIdx.x&15, ty = threadIdx.x>>4;
  const int n0 = blockIdx.y<<4, k0 = blockIdx.x<<4;
  float s = 0.f;
  for (int j0=0;j0<512;j0+=16){
    As[ty][tx] = posW0[(size_t)(n0+ty)*1024 + 512 + j0+tx];
    Bs[ty][tx] = encW2[(size_t)(j0+ty)*512 + k0+tx];
    __syncthreads();
    #pragma unroll
    for (int jj=0;jj<16;jj++) s += As[ty][jj]*Bs[jj][tx];
    __syncthreads();
  }
  wce[(size_t)(n0+ty)*512 + k0+tx] = s;
}
__global__ void k_bce(const float* __restrict__ posW0, const float* __restrict__ eb2,
                      float* __restrict__ bce){
  const int n = threadIdx.x;
  float s=0.f;
  for (int j=0;j<512;j++) s += posW0[(size_t)n*1024 + 512 + j]*eb2[j];
  bce[n]=s;
}

// ---------------- fused encoder: obs -> penc (rows in (t,b) order) ----------------
__global__ __launch_bounds__(512,1) void k_enc(
    const float* __restrict__ obs,
    const short* __restrict__ w0, const short* __restrict__ w1, const short* __restrict__ w2,
    const float* __restrict__ b0v, const float* __restrict__ b1v, const float* __restrict__ bcev,
    short* __restrict__ penc)
{
  __shared__ short x0[64][264];
  __shared__ short x1[64][520];
  const int tid=threadIdx.x, lane=tid&63, wid=tid>>6;
  const int wm=wid&1, wn=wid>>1;
  const size_t m0 = (size_t)blockIdx.x<<6;
  {
    const int row = tid>>3, cb = (tid&7)<<5;
    const size_t r = m0 + row;
    const float* sp = obs + (((r&1023)<<7) + (r>>10))*256 + cb;
    #pragma unroll
    for (int u=0;u<8;u++){
      float4_ v = *(const float4_*)(sp + (u<<2));
      short4_ s;
      #pragma unroll
      for (int e=0;e<4;e++) s[e]=f2b(v[e]);
      *(short4_*)(&x0[row][cb+(u<<2)]) = s;
    }
  }
  __syncthreads();
  float4_ acc[2][8];
  // L1 (K=256)
  #pragma unroll
  for (int am=0;am<2;am++)
    #pragma unroll
    for (int nj=0;nj<8;nj++) acc[am][nj]=(float4_)(0.f);
  for (int kf=0;kf<8;++kf){
    short8 a0 = *(const short8*)(&x0[(wm<<5)+(lane&15)][(kf<<5)+((lane>>4)<<3)]);
    short8 a1 = *(const short8*)(&x0[(wm<<5)+16+(lane&15)][(kf<<5)+((lane>>4)<<3)]);
    #pragma unroll
    for (int nj=0;nj<8;nj++){
      short8 b = ldB(w0, (wn<<3)+nj, kf, 8, lane);
      acc[0][nj] = mfma16(a0,b,acc[0][nj]);
      acc[1][nj] = mfma16(a1,b,acc[1][nj]);
    }
  }
  #pragma unroll
  for (int am=0;am<2;am++)
    #pragma unroll
    for (int nj=0;nj<8;nj++){
      const int col=(wn<<7)+(nj<<4)+(lane&15);
      const float bs=b0v[col];
      #pragma unroll
      for (int e=0;e<4;e++)
        x1[(wm<<5)+(am<<4)+((lane>>4)<<2)+e][col]=f2b(elu_(acc[am][nj][e]+bs));
    }
  __syncthreads();
  // L2 (K=512)
  #pragma unroll
  for (int am=0;am<2;am++)
    #pragma unroll
    for (int nj=0;nj<8;nj++) acc[am][nj]=(float4_)(0.f);
  for (int kf=0;kf<16;++kf){
    short8 a0 = *(const short8*)(&x1[(wm<<5)+(lane&15)][(kf<<5)+((lane>>4)<<3)]);
    short8 a1 = *(const short8*)(&x1[(wm<<5)+16+(lane&15)][(kf<<5)+((lane>>4)<<3)]);
    #pragma unroll
    for (int nj=0;nj<8;nj++){
      short8 b = ldB(w1, (wn<<3)+nj, kf, 16, lane);
      acc[0][nj] = mfma16(a0,b,acc[0][nj]);
      acc[1][nj] = mfma16(a1,b,acc[1][nj]);
    }
  }
  __syncthreads();
  #pragma unroll
  for (int am=0;am<2;am++)
    #pragma unroll
    for (int nj=0;nj<8;nj++){
      const int col=(wn<<7)+(nj<<4)+(lane&15);
      const float bs=b1v[col];
      #pragma unroll
      for (int e=0;e<4;e++)
        x1[(wm<<5)+(am<<4)+((lane>>4)<<2)+e][col]=f2b(elu_(acc[am][nj][e]+bs));
    }
  __syncthreads();
  // L3 (K=512) -> penc
  #pragma unroll
  for (int am=0;am<2;am++)
    #pragma unroll
    for (int nj=0;nj<8;nj++) acc[am][nj]=(float4_)(0.f);
  for (int kf=0;kf<16;++kf){
    short8 a0 = *(const short8*)(&x1[(wm<<5)+(lane&15)][(kf<<5)+((lane>>4)<<3)]);
    short8 a1 = *(const short8*)(&x1[(wm<<5)+16+(lane&15)][(kf<<5)+((lane>>4)<<3)]);
    #pragma unroll
    for (int nj=0;nj<8;nj++){
      short8 b = ldB(w2, (wn<<3)+nj, kf, 16, lane);
      acc[0][nj] = mfma16(a0,b,acc[0][nj]);
      acc[1][nj] = mfma16(a1,b,acc[1][nj]);
    }
  }
  #pragma unroll
  for (int am=0;am<2;am++)
    #pragma unroll
    for (int nj=0;nj<8;nj++){
      const int col=(wn<<7)+(nj<<4)+(lane&15);
      const float bs=bcev[col];
      #pragma unroll
      for (int e=0;e<4;e++){
        const int row=(wm<<5)+(am<<4)+((lane>>4)<<2)+e;
        penc[(m0+row)*512 + col] = f2b(acc[am][nj][e]+bs);
      }
    }
}

// ---------------- persistent scan kernel ----------------
union ScanSmem {
  short stg[2][14*512];
  struct { float ef[16][260]; short z[16][72]; } p3;
};

__global__ __launch_bounds__(512,1) void k_scan(
    const float* __restrict__ eps, const short* __restrict__ penc,
    const short* __restrict__ W1cat,
    const short* __restrict__ priW1, const short* __restrict__ posW1,
    const short* __restrict__ priW2, const short* __restrict__ posW2,
    const short* __restrict__ Wih,
    const float* __restrict__ pri_b0, const float* __restrict__ pos_b0,
    const float* __restrict__ bhh,
    const float* __restrict__ pri_b1, const float* __restrict__ pos_b1,
    const float* __restrict__ pri_b2, const float* __restrict__ pos_b2,
    const float* __restrict__ bih,
    float* __restrict__ hfrag, short* __restrict__ hbf,
    short* __restrict__ Abuf, short* __restrict__ Bbuf,
    short* __restrict__ Cbuf, short* __restrict__ Dbuf,
    float* __restrict__ Gfrag, short* __restrict__ zall,
    float* __restrict__ out_kls, float* __restrict__ out_mu,
    unsigned* __restrict__ ctrl)
{
  __shared__ ScanSmem sm;
  const int tid = threadIdx.x, lane = tid&63, wid = tid>>6;
  const int blk = blockIdx.x;
  unsigned epoch = 0;

  for (int t=0; t<128; ++t){
    // ============ P1: A=pri0(h), B=pos0(h)+penc, G=h@Whh^T ============
    {
      const int bm = blk>>4, bn = blk&15;
      const int m0 = bm<<6;
      const int wm = wid&3, wh = wid>>2;
      float4_ acc[5];
      #pragma unroll
      for (int j=0;j<5;j++) acc[j]=(float4_)(0.f);
      auto stage = [&](int kf){
        for (int s=tid; s<896; s+=512){
          const int f = s>>6, l = s&63;
          short8 v;
          if (f<4) v = ldA(hbf, 512, m0 + (f<<4), kf<<5, l);
          else     v = ldB(W1cat, bn*10 + (f-4), kf, 16, l);
          *(short8*)(&sm.stg[kf&1][(f<<9) + (l<<3)]) = v;
        }
      };
      stage(0);
      for (int kf=0; kf<16; ++kf){
        __syncthreads();
        if (kf<15) stage(kf+1);
        const short* bufp = sm.stg[kf&1];
        short8 a = *(const short8*)(bufp + (wm<<9) + (lane<<3));
        #pragma unroll
        for (int j=0;j<5;j++){
          short8 b = *(const short8*)(bufp + ((4 + wh*5 + j)<<9) + (lane<<3));
          acc[j] = mfma16(a,b,acc[j]);
        }
      }
      const int mrow = m0 + (wm<<4) + ((lane>>4)<<2);
      #pragma unroll
      for (int j=0;j<5;j++){
        const int nfl = wh*5 + j;
        const int c0 = bn*160 + (nfl<<4);
        const int c  = c0 + (lane&15);
        if (c0 < 512){
          const float bs = pri_b0[c];
          #pragma unroll
          for (int e=0;e<4;e++)
            Abuf[(size_t)(mrow+e)*512 + c] = f2b(elu_(acc[j][e] + bs));
        } else if (c0 < 1024){
          const float bs = pos_b0[c-512];
          #pragma unroll
          for (int e=0;e<4;e++){
            float v = acc[j][e] + bs + b2f(penc[((size_t)t*1024 + (mrow+e))*512 + (c-512)]);
            Bbuf[(size_t)(mrow+e)*512 + (c-512)] = f2b(elu_(v));
          }
        } else {
          const float bs = bhh[c-1024];
          float4_ g;
          #pragma unroll
          for (int e=0;e<4;e++) g[e] = acc[j][e] + bs;
          const int mf = (m0>>4) + wm;
          const int nf = (c0-1024)>>4;
          *(float4_*)(Gfrag + (((size_t)mf*96 + nf)<<8) + (lane<<2)) = g;
        }
      }
    }
    { // barrier
      __syncthreads();
      epoch++;
      if (tid==0){
        __hip_atomic_fetch_add(ctrl, 1u, __ATOMIC_ACQ_REL, __HIP_MEMORY_SCOPE_AGENT);
        while (__hip_atomic_load(ctrl, __ATOMIC_ACQUIRE, __HIP_MEMORY_SCOPE_AGENT) < epoch*GRIDN)
          __builtin_amdgcn_s_sleep(1);
      }
      __syncthreads();
    }
    // ============ P2: C=pri1(A), D=pos1(B) ============
    {
      const int bm = blk>>4, bn = blk&15;
      const int m0 = bm<<6;
      const int wm = wid&3, wn = wid>>2;
      const short* src = (bn<8)? Abuf : Bbuf;
      const short* Wsz = (bn<8)? priW1 : posW1;
      const float* bb  = (bn<8)? pri_b1 : pos_b1;
      short* dst = (bn<8)? Cbuf : Dbuf;
      const int nfb = (bn&7)<<2;
      float4_ acc[2];
      acc[0]=(float4_)(0.f); acc[1]=(float4_)(0.f);
      auto stage = [&](int kf){
        const int f = tid>>6, l = tid&63;
        short8 v;
        if (f<4) v = ldA(src, 512, m0+(f<<4), kf<<5, l);
        else     v = ldB(Wsz, nfb + (f-4), kf, 16, l);
        *(short8*)(&sm.stg[kf&1][(f<<9)+(l<<3)]) = v;
      };
      stage(0);
      for (int kf=0;kf<16;++kf){
        __syncthreads();
        if (kf<15) stage(kf+1);
        const short* bufp = sm.stg[kf&1];
        short8 a = *(const short8*)(bufp + (wm<<9) + (lane<<3));
        #pragma unroll
        for (int j=0;j<2;j++){
          short8 b = *(const short8*)(bufp + ((4 + (wn<<1) + j)<<9) + (lane<<3));
          acc[j] = mfma16(a,b,acc[j]);
        }
      }
      const int mrow = m0 + (wm<<4) + ((lane>>4)<<2);
      #pragma unroll
      for (int j=0;j<2;j++){
        const int cl = ((nfb + (wn<<1) + j)<<4) + (lane&15);
        const float bs = bb[cl];
        #pragma unroll
        for (int e=0;e<4;e++)
          dst[(size_t)(mrow+e)*512 + cl] = f2b(elu_(acc[j][e] + bs));
      }
    }
    { // barrier
      __syncthreads();
      epoch++;
      if (tid==0){
        __hip_atomic_fetch_add(ctrl, 1u, __ATOMIC_ACQ_REL, __HIP_MEMORY_SCOPE_AGENT);
        while (__hip_atomic_load(ctrl, __ATOMIC_ACQUIRE, __HIP_MEMORY_SCOPE_AGENT) < epoch*GRIDN)
          __builtin_amdgcn_s_sleep(1);
      }
      __syncthreads();
    }
    // ============ P3: tail (64 blocks x 16 rows) ============
    if (blk < 64){
      const int m0 = blk<<4;
      {
        const int isF = wid>>2, nf2 = (wid&3)<<1;
        const short* src = isF? Dbuf : Cbuf;
        const short* Wsz = isF? posW2 : priW2;
        const float* bb  = isF? pos_b2 : pri_b2;
        float4_ acc[2];
        acc[0]=(float4_)(0.f); acc[1]=(float4_)(0.f);
        for (int kf=0;kf<16;++kf){
          short8 a = ldA(src, 512, m0, kf<<5, lane);
          #pragma unroll
          for (int j=0;j<2;j++)
            acc[j] = mfma16(a, ldB(Wsz, nf2+j, kf, 16, lane), acc[j]);
        }
        const int r0 = (lane>>4)<<2;
        #pragma unroll
        for (int j=0;j<2;j++){
          const int cl = ((nf2+j)<<4) + (lane&15);
          const float bs = bb[cl];
          #pragma unroll
          for (int e=0;e<4;e++)
            sm.p3.ef[r0+e][isF*128 + cl] = acc[j][e] + bs;
        }
      }
      __syncthreads();
      {
        const int row = tid>>5, q = tid&31;
        const int b_ = m0 + row;
        float kl2 = 0.f;
        #pragma unroll
        for (int d=0; d<2; ++d){
          const int j = (q<<1) + d;
          const float mp = sm.p3.ef[row][j],     lp = sm.p3.ef[row][64+j];
          const float mq = sm.p3.ef[row][128+j], lq = sm.p3.ef[row][192+j];
          const float ev = eps[((size_t)b_*128 + t)*64 + j];
          const float zv = mq + __expf(lq)*ev;
          const short zb = f2b(zv);
          sm.p3.z[row][j] = zb;
          zall[((size_t)t*1024 + b_)*64 + j] = zb;
          out_mu[((size_t)b_*128 + t)*64 + j] = mq;
          const float dd = mq-mp;
          kl2 += lp - lq + (__expf(2.f*lq) + dd*dd)/(2.f*__expf(2.f*lp)) - 0.5f;
        }
        #pragma unroll
        for (int off=16; off; off>>=1) kl2 += __shfl_xor(kl2, off, 32);
        if (q==0) out_kls[(size_t)b_*128 + t] = kl2;
      }
      __syncthreads();
      {
        short8 za0 = *(const short8*)(&sm.p3.z[lane&15][((lane>>4)<<3)]);
        short8 za1 = *(const short8*)(&sm.p3.z[lane&15][32 + ((lane>>4)<<3)]);
        float4_ gacc[3][4];
        #pragma unroll
        for (int s=0;s<3;s++)
          #pragma unroll
          for (int j4=0;j4<4;j4++){
            gacc[s][j4] = (float4_)(0.f);
            const int nf = s*32 + (wid<<2) + j4;
            gacc[s][j4] = mfma16(za0, ldB(Wih, nf, 0, 2, lane), gacc[s][j4]);
            gacc[s][j4] = mfma16(za1, ldB(Wih, nf, 1, 2, lane), gacc[s][j4]);
          }
        const int mf = blk;
        #pragma unroll
        for (int j4=0;j4<4;j4++){
          const int ccol = (wid<<6) + (j4<<4) + (lane&15);
          const float br = bih[ccol], bz = bih[512+ccol], bn_ = bih[1024+ccol];
          const int nfh = (wid<<2) + j4;
          float4_ gr = *(const float4_*)(Gfrag + (((size_t)mf*96 + nfh)<<8) + (lane<<2));
          float4_ gz = *(const float4_*)(Gfrag + (((size_t)mf*96 + 32 + nfh)<<8) + (lane<<2));
          float4_ gn = *(const float4_*)(Gfrag + (((size_t)mf*96 + 64 + nfh)<<8) + (lane<<2));
          float* hp = hfrag + (((size_t)mf*32 + nfh)<<8) + (lane<<2);
          float4_ hold = *(const float4_*)hp;
          float4_ hnew;
          #pragma unroll
          for (int e=0;e<4;e++){
            const float r  = sigm_(gacc[0][j4][e] + br + gr[e]);
            const float zg = sigm_(gacc[1][j4][e] + bz + gz[e]);
            const float nn = tanh_(gacc[2][j4][e] + bn_ + r*gn[e]);
            hnew[e] = (1.f-zg)*nn + zg*hold[e];
          }
          *(float4_*)hp = hnew;
          const int mrow = m0 + ((lane>>4)<<2);
          #pragma unroll
          for (int e=0;e<4;e++)
            hbf[(size_t)(mrow+e)*512 + ccol] = f2b(hnew[e]);
        }
      }
    }
    { // barrier
      __syncthreads();
      epoch++;
      if (tid==0){
        __hip_atomic_fetch_add(ctrl, 1u, __ATOMIC_ACQ_REL, __HIP_MEMORY_SCOPE_AGENT);
        while (__hip_atomic_load(ctrl, __ATOMIC_ACQUIRE, __HIP_MEMORY_SCOPE_AGENT) < epoch*GRIDN)
          __builtin_amdgcn_s_sleep(1);
      }
      __syncthreads();
    }
  }
}

// ---------------- fused decoder: z -> recons ----------------
__global__ __launch_bounds__(512,1) void k_dec(
    const short* __restrict__ zall,
    const short* __restrict__ w0, const short* __restrict__ w1, const short* __restrict__ w2,
    const float* __restrict__ b0v, const float* __restrict__ b1v, const float* __restrict__ b2v,
    float* __restrict__ rec)
{
  __shared__ short zf[64][72];
  __shared__ short x1[64][520];
  const int tid=threadIdx.x, lane=tid&63, wid=tid>>6;
  const int wm=wid&1, wn=wid>>1;
  const size_t m0 = (size_t)blockIdx.x<<6;
  {
    const int row = tid>>3, ch = (tid&7)<<3;
    *(short8*)(&zf[row][ch]) = *(const short8*)(zall + (m0+row)*64 + ch);
  }
  __syncthreads();
  float4_ acc[2][8];
  // L1 (K=64)
  #pragma unroll
  for (int am=0;am<2;am++)
    #pragma unroll
    for (int nj=0;nj<8;nj++) acc[am][nj]=(float4_)(0.f);
  for (int kf=0;kf<2;++kf){
    short8 a0 = *(const short8*)(&zf[(wm<<5)+(lane&15)][(kf<<5)+((lane>>4)<<3)]);
    short8 a1 = *(const short8*)(&zf[(wm<<5)+16+(lane&15)][(kf<<5)+((lane>>4)<<3)]);
    #pragma unroll
    for (int nj=0;nj<8;nj++){
      short8 b = ldB(w0, (wn<<3)+nj, kf, 2, lane);
      acc[0][nj] = mfma16(a0,b,acc[0][nj]);
      acc[1][nj] = mfma16(a1,b,acc[1][nj]);
    }
  }
  #pragma unroll
  for (int am=0;am<2;am++)
    #pragma unroll
    for (int nj=0;nj<8;nj++){
      const int col=(wn<<7)+(nj<<4)+(lane&15);
      const float bs=b0v[col];
      #pragma unroll
      for (int e=0;e<4;e++)
        x1[(wm<<5)+(am<<4)+((lane>>4)<<2)+e][col]=f2b(elu_(acc[am][nj][e]+bs));
    }
  __syncthreads();
  // L2 (K=512)
  #pragma unroll
  for (int am=0;am<2;am++)
    #pragma unroll
    for (int nj=0;nj<8;nj++) acc[am][nj]=(float4_)(0.f);
  for (int kf=0;kf<16;++kf){
    short8 a0 = *(const short8*)(&x1[(wm<<5)+(lane&15)][(kf<<5)+((lane>>4)<<3)]);
    short8 a1 = *(const short8*)(&x1[(wm<<5)+16+(lane&15)][(kf<<5)+((lane>>4)<<3)]);
    #pragma unroll
    for (int nj=0;nj<8;nj++){
      short8 b = ldB(w1, (wn<<3)+nj, kf, 16, lane);
      acc[0][nj] = mfma16(a0,b,acc[0][nj]);
      acc[1][nj] = mfma16(a1,b,acc[1][nj]);
    }
  }
  __syncthreads();
  #pragma unroll
  for (int am=0;am<2;am++)
    #pragma unroll
    for (int nj=0;nj<8;nj++){
      const int col=(wn<<7)+(nj<<4)+(lane&15);
      const float bs=b1v[col];
      #pragma unroll
      for (int e=0;e<4;e++)
        x1[(wm<<5)+(am<<4)+((lane>>4)<<2)+e][col]=f2b(elu_(acc[am][nj][e]+bs));
    }
  __syncthreads();
  // L3 (K=512, N=256) -> rec with (t,b)->(b,t) permute
  float4_ a3[2][4];
  #pragma unroll
  for (int am=0;am<2;am++)
    #pragma unroll
    for (int nj=0;nj<4;nj++) a3[am][nj]=(float4_)(0.f);
  for (int kf=0;kf<16;++kf){
    short8 a0 = *(const short8*)(&x1[(wm<<5)+(lane&15)][(kf<<5)+((lane>>4)<<3)]);
    short8 a1 = *(const short8*)(&x1[(wm<<5)+16+(lane&15)][(kf<<5)+((lane>>4)<<3)]);
    #pragma unroll
    for (int nj=0;nj<4;nj++){
      short8 b = ldB(w2, (wn<<2)+nj, kf, 16, lane);
      a3[0][nj] = mfma16(a0,b,a3[0][nj]);
      a3[1][nj] = mfma16(a1,b,a3[1][nj]);
    }
  }
  #pragma unroll
  for (int am=0;am<2;am++)
    #pragma unroll
    for (int nj=0;nj<4;nj++){
      const int col=(wn<<6)+(nj<<4)+(lane&15);
      const float bs=b2v[col];
      #pragma unroll
      for (int e=0;e<4;e++){
        const int row=(wm<<5)+(am<<4)+((lane>>4)<<2)+e;
        const size_t r = m0+row;
        rec[(((r&1023)<<7) + (r>>10))*256 + col] = a3[am][nj][e]+bs;
      }
    }
}

extern "C" void kernel_launch(void* const* d_in, const int* in_sizes, int n_in,
                              void* d_out, int out_size, void* d_ws, size_t ws_size,
                              hipStream_t stream)
{
  (void)in_sizes; (void)n_in; (void)out_size; (void)ws_size;
  const float* obs = (const float*)d_in[0];
  const float* eps = (const float*)d_in[1];
  const float* eW0 = (const float*)d_in[2];
  const float* eb0 = (const float*)d_in[3];
  const float* eW1 = (const float*)d_in[4];
  const float* eb1 = (const float*)d_in[5];
  const float* eW2 = (const float*)d_in[6];
  const float* eb2 = (const float*)d_in[7];
  const float* pW0 = (const float*)d_in[8];
  const float* pb0 = (const float*)d_in[9];
  const float* pW1 = (const float*)d_in[10];
  const float* pb1 = (const float*)d_in[11];
  const float* pW2 = (const float*)d_in[12];
  const float* pb2 = (const float*)d_in[13];
  const float* qW0 = (const float*)d_in[14];
  const float* qb0 = (const float*)d_in[15];
  const float* qW1 = (const float*)d_in[16];
  const float* qb1 = (const float*)d_in[17];
  const float* qW2 = (const float*)d_in[18];
  const float* qb2 = (const float*)d_in[19];
  const float* dW0 = (const float*)d_in[20];
  const float* db0 = (const float*)d_in[21];
  const float* dW1 = (const float*)d_in[22];
  const float* db1 = (const float*)d_in[23];
  const float* dW2 = (const float*)d_in[24];
  const float* db2 = (const float*)d_in[25];
  const float* gWih = (const float*)d_in[26];
  const float* gbih = (const float*)d_in[27];
  const float* gWhh = (const float*)d_in[28];
  const float* gbhh = (const float*)d_in[29];

  float* out_rec = (float*)d_out;
  float* out_kls = out_rec + (size_t)1024*128*256;
  float* out_mu  = out_kls + (size_t)1024*128;

  char* w = (char*)d_ws;
  auto alloc = [&](size_t bytes)->char*{ char* p=w; w += (bytes+255)&~(size_t)255; return p; };
  unsigned* ctrl = (unsigned*)alloc(4096);
  short* W1cat  = (short*)alloc((size_t)1310720*2);
  short* priW1s = (short*)alloc((size_t)262144*2);
  short* posW1s = (short*)alloc((size_t)262144*2);
  short* priW2s = (short*)alloc((size_t)65536*2);
  short* posW2s = (short*)alloc((size_t)65536*2);
  short* Wihs   = (short*)alloc((size_t)98304*2);
  short* encW0s = (short*)alloc((size_t)131072*2);
  short* encW1s = (short*)alloc((size_t)262144*2);
  short* wces   = (short*)alloc((size_t)262144*2);
  short* decW0s = (short*)alloc((size_t)32768*2);
  short* decW1s = (short*)alloc((size_t)262144*2);
  short* decW2s = (short*)alloc((size_t)131072*2);
  float* wce_rm = (float*)alloc((size_t)262144*4);
  float* bce    = (float*)alloc(512*4);
  float* hfrag  = (float*)alloc((size_t)524288*4);
  short* hbf    = (short*)alloc((size_t)524288*2);
  short* Abuf   = (short*)alloc((size_t)524288*2);
  short* Bbuf   = (short*)alloc((size_t)524288*2);
  short* Cbuf   = (short*)alloc((size_t)524288*2);
  short* Dbuf   = (short*)alloc((size_t)524288*2);
  float* Gfrag  = (float*)alloc((size_t)1572864*4);
  short* zall   = (short*)alloc((size_t)8388608*2);
  short* penc   = (short*)alloc((size_t)67108864*2);

  k_init<<<2048,256,0,stream>>>(ctrl, hfrag, hbf);
  k_swz<<<dim3(16,32),64,0,stream>>>(pW0,  W1cat, 512, 0,  0, 16);
  k_swz<<<dim3(16,32),64,0,stream>>>(qW0,  W1cat, 1024,0, 32, 16);
  k_swz<<<dim3(16,96),64,0,stream>>>(gWhh, W1cat, 512, 0, 64, 16);
  k_swz<<<dim3(16,32),64,0,stream>>>(pW1, priW1s, 512,0,0,16);
  k_swz<<<dim3(16,32),64,0,stream>>>(qW1, posW1s, 512,0,0,16);
  k_swz<<<dim3(16,8 ),64,0,stream>>>(pW2, priW2s, 512,0,0,16);
  k_swz<<<dim3(16,8 ),64,0,stream>>>(qW2, posW2s, 512,0,0,16);
  k_swz<<<dim3(2,96 ),64,0,stream>>>(gWih, Wihs, 64,0,0,2);
  k_swz<<<dim3(8,32 ),64,0,stream>>>(eW0, encW0s, 256,0,0,8);
  k_swz<<<dim3(16,32),64,0,stream>>>(eW1, encW1s, 512,0,0,16);
  k_swz<<<dim3(2,32 ),64,0,stream>>>(dW0, decW0s, 64,0,0,2);
  k_swz<<<dim3(16,32),64,0,stream>>>(dW1, decW1s, 512,0,0,16);
  k_swz<<<dim3(16,16),64,0,stream>>>(dW2, decW2s, 512,0,0,16);
  k_wce<<<dim3(32,32),256,0,stream>>>(qW0, eW2, wce_rm);
  k_bce<<<1,512,0,stream>>>(qW0, eb2, bce);
  k_swz<<<dim3(16,32),64,0,stream>>>(wce_rm, wces, 512,0,0,16);
  k_enc<<<2048,512,0,stream>>>(obs, encW0s, encW1s, wces, eb0, eb1, bce, penc);
  k_scan<<<GRIDN,512,0,stream>>>(eps, penc, W1cat, priW1s, posW1s, priW2s, posW2s, Wihs,
      pb0, qb0, gbhh, pb1, qb1, pb2, qb2, gbih,
      hfrag, hbf, Abuf, Bbuf, Cbuf, Dbuf, Gfrag, zall, out_kls, out_mu, ctrl);
  k_dec<<<2048,512,0,stream>>>(zall, decW0s, decW1s, decW2s, db0, db1, db2, out_rec);
}

// Round 2
// 12535.297 us; speedup vs baseline: 2.4050x; 2.4050x over previous
//
#include <hip/hip_runtime.h>
#include <hip/hip_bf16.h>

#define DI __device__ __forceinline__
#define GRIDN 256

typedef short short8 __attribute__((ext_vector_type(8)));
typedef short short4_ __attribute__((ext_vector_type(4)));
typedef float float4_ __attribute__((ext_vector_type(4)));

DI float4_ mfma16(short8 a, short8 b, float4_ c){
  return __builtin_amdgcn_mfma_f32_16x16x32_bf16(a, b, c, 0, 0, 0);
}
DI short f2b(float x){
  unsigned u = __builtin_bit_cast(unsigned, x);
  u += 0x7fffu + ((u>>16)&1u);
  return (short)(u>>16);
}
DI float b2f(short x){
  unsigned u = ((unsigned)(unsigned short)x)<<16;
  return __builtin_bit_cast(float, u);
}
DI float elu_(float x){ return x>0.f ? x : (__expf(x)-1.f); }
DI float sigm_(float x){ return 1.f/(1.f+__expf(-x)); }
DI float tanh_(float x){ float e=__expf(2.f*x); return 1.f-2.f/(e+1.f); }

DI short8 ldA(const short* base, int ld, int row0, int k0, int lane){
  return *(const short8*)(base + (size_t)(row0 + (lane&15))*ld + k0 + ((lane>>4)<<3));
}
DI short8 ldB(const short* swz, int nf, int kf, int KF, int lane){
  return *(const short8*)(swz + (((size_t)nf*KF + kf)<<9) + (lane<<3));
}

// ---------------- init: zero ctrl + h ----------------
__global__ void k_init(unsigned* ctrl, float* hfrag, short* hbf){
  size_t i = (size_t)blockIdx.x*blockDim.x + threadIdx.x;
  if (i < 8448) ctrl[i] = 0u;
  if (i < 524288){ hfrag[i] = 0.f; hbf[i] = 0; }
}

// ---------------- weight swizzle: row-major f32 (N,K) -> frag layout ----------------
__global__ void k_swz(const float* __restrict__ src, short* __restrict__ dst,
                      int stride, int coloff, int nfoff, int KF){
  const int kf = blockIdx.x, nf = blockIdx.y, l = threadIdx.x;
  const float* p = src + (size_t)((nf<<4) + (l&15))*stride + coloff + (kf<<5) + ((l>>4)<<3);
  short8 v;
  #pragma unroll
  for (int e=0;e<8;e++) v[e]=f2b(p[e]);
  *(short8*)(dst + (((size_t)(nfoff+nf)*KF + kf)<<9) + (l<<3)) = v;
}

// ---------------- Wce = posW0e @ encW2 (f32, small) ----------------
__global__ void k_wce(const float* __restrict__ posW0, const float* __restrict__ encW2,
                      float* __restrict__ wce){
  __shared__ float As[16][17], Bs[16][17];
  const int tx = threadIdx.x&15, ty = threadIdx.x>>4;
  const int n0 = blockIdx.y<<4, k0 = blockIdx.x<<4;
  float s = 0.f;
  for (int j0=0;j0<512;j0+=16){
    As[ty][tx] = posW0[(size_t)(n0+ty)*1024 + 512 + j0+tx];
    Bs[ty][tx] = encW2[(size_t)(j0+ty)*512 + k0+tx];
    __syncthreads();
    #pragma unroll
    for (int jj=0;jj<16;jj++) s += As[ty][jj]*Bs[jj][tx];
    __syncthreads();
  }
  wce[(size_t)(n0+ty)*512 + k0+tx] = s;
}
__global__ void k_bce(const float* __restrict__ posW0, const float* __restrict__ eb2,
                      float* __restrict__ bce){
  const int n = threadIdx.x;
  float s=0.f;
  for (int j=0;j<512;j++) s += posW0[(size_t)n*1024 + 512 + j]*eb2[j];
  bce[n]=s;
}

// ---------------- fused encoder: obs -> penc (rows in (t,b) order) ----------------
__global__ __launch_bounds__(512,1) void k_enc(
    const float* __restrict__ obs,
    const short* __restrict__ w0, const short* __restrict__ w1, const short* __restrict__ w2,
    const float* __restrict__ b0v, const float* __restrict__ b1v, const float* __restrict__ bcev,
    short* __restrict__ penc)
{
  __shared__ short x0[64][264];
  __shared__ short x1[64][520];
  const int tid=threadIdx.x, lane=tid&63, wid=tid>>6;
  const int wm=wid&1, wn=wid>>1;
  const size_t m0 = (size_t)blockIdx.x<<6;
  {
    const int row = tid>>3, cb = (tid&7)<<5;
    const size_t r = m0 + row;
    const float* sp = obs + (((r&1023)<<7) + (r>>10))*256 + cb;
    #pragma unroll
    for (int u=0;u<8;u++){
      float4_ v = *(const float4_*)(sp + (u<<2));
      short4_ s;
      #pragma unroll
      for (int e=0;e<4;e++) s[e]=f2b(v[e]);
      *(short4_*)(&x0[row][cb+(u<<2)]) = s;
    }
  }
  __syncthreads();
  float4_ acc[2][8];
  // L1 (K=256)
  #pragma unroll
  for (int am=0;am<2;am++)
    #pragma unroll
    for (int nj=0;nj<8;nj++) acc[am][nj]=(float4_)(0.f);
  for (int kf=0;kf<8;++kf){
    short8 a0 = *(const short8*)(&x0[(wm<<5)+(lane&15)][(kf<<5)+((lane>>4)<<3)]);
    short8 a1 = *(const short8*)(&x0[(wm<<5)+16+(lane&15)][(kf<<5)+((lane>>4)<<3)]);
    #pragma unroll
    for (int nj=0;nj<8;nj++){
      short8 b = ldB(w0, (wn<<3)+nj, kf, 8, lane);
      acc[0][nj] = mfma16(a0,b,acc[0][nj]);
      acc[1][nj] = mfma16(a1,b,acc[1][nj]);
    }
  }
  #pragma unroll
  for (int am=0;am<2;am++)
    #pragma unroll
    for (int nj=0;nj<8;nj++){
      const int col=(wn<<7)+(nj<<4)+(lane&15);
      const float bs=b0v[col];
      #pragma unroll
      for (int e=0;e<4;e++)
        x1[(wm<<5)+(am<<4)+((lane>>4)<<2)+e][col]=f2b(elu_(acc[am][nj][e]+bs));
    }
  __syncthreads();
  // L2 (K=512)
  #pragma unroll
  for (int am=0;am<2;am++)
    #pragma unroll
    for (int nj=0;nj<8;nj++) acc[am][nj]=(float4_)(0.f);
  for (int kf=0;kf<16;++kf){
    short8 a0 = *(const short8*)(&x1[(wm<<5)+(lane&15)][(kf<<5)+((lane>>4)<<3)]);
    short8 a1 = *(const short8*)(&x1[(wm<<5)+16+(lane&15)][(kf<<5)+((lane>>4)<<3)]);
    #pragma unroll
    for (int nj=0;nj<8;nj++){
      short8 b = ldB(w1, (wn<<3)+nj, kf, 16, lane);
      acc[0][nj] = mfma16(a0,b,acc[0][nj]);
      acc[1][nj] = mfma16(a1,b,acc[1][nj]);
    }
  }
  __syncthreads();
  #pragma unroll
  for (int am=0;am<2;am++)
    #pragma unroll
    for (int nj=0;nj<8;nj++){
      const int col=(wn<<7)+(nj<<4)+(lane&15);
      const float bs=b1v[col];
      #pragma unroll
      for (int e=0;e<4;e++)
        x1[(wm<<5)+(am<<4)+((lane>>4)<<2)+e][col]=f2b(elu_(acc[am][nj][e]+bs));
    }
  __syncthreads();
  // L3 (K=512) -> penc
  #pragma unroll
  for (int am=0;am<2;am++)
    #pragma unroll
    for (int nj=0;nj<8;nj++) acc[am][nj]=(float4_)(0.f);
  for (int kf=0;kf<16;++kf){
    short8 a0 = *(const short8*)(&x1[(wm<<5)+(lane&15)][(kf<<5)+((lane>>4)<<3)]);
    short8 a1 = *(const short8*)(&x1[(wm<<5)+16+(lane&15)][(kf<<5)+((lane>>4)<<3)]);
    #pragma unroll
    for (int nj=0;nj<8;nj++){
      short8 b = ldB(w2, (wn<<3)+nj, kf, 16, lane);
      acc[0][nj] = mfma16(a0,b,acc[0][nj]);
      acc[1][nj] = mfma16(a1,b,acc[1][nj]);
    }
  }
  #pragma unroll
  for (int am=0;am<2;am++)
    #pragma unroll
    for (int nj=0;nj<8;nj++){
      const int col=(wn<<7)+(nj<<4)+(lane&15);
      const float bs=bcev[col];
      #pragma unroll
      for (int e=0;e<4;e++){
        const int row=(wm<<5)+(am<<4)+((lane>>4)<<2)+e;
        penc[(m0+row)*512 + col] = f2b(acc[am][nj][e]+bs);
      }
    }
}

// ---------------- persistent scan kernel ----------------
union ScanSmem {
  short stg[2][14*512];
  struct { float ef[16][260]; short z[16][72]; } p3;
};

__global__ __launch_bounds__(512,1) void k_scan(
    const float* __restrict__ eps, const short* __restrict__ penc,
    const short* __restrict__ W1cat,
    const short* __restrict__ priW1, const short* __restrict__ posW1,
    const short* __restrict__ priW2, const short* __restrict__ posW2,
    const short* __restrict__ Wih,
    const float* __restrict__ pri_b0, const float* __restrict__ pos_b0,
    const float* __restrict__ bhh,
    const float* __restrict__ pri_b1, const float* __restrict__ pos_b1,
    const float* __restrict__ pri_b2, const float* __restrict__ pos_b2,
    const float* __restrict__ bih,
    float* __restrict__ hfrag, short* __restrict__ hbf,
    short* __restrict__ Abuf, short* __restrict__ Bbuf,
    short* __restrict__ Cbuf, short* __restrict__ Dbuf,
    float* __restrict__ Gfrag, short* __restrict__ zall,
    float* __restrict__ out_kls, float* __restrict__ out_mu,
    unsigned* __restrict__ ctrl)
{
  __shared__ ScanSmem sm;
  const int tid = threadIdx.x, lane = tid&63, wid = tid>>6;
  const int blk = blockIdx.x;
  unsigned epoch = 0;

  // Contention-free hierarchical grid barrier:
  //  - each block: ONE release fence (wbl2) + relaxed flag store to its OWN cacheline
  //  - block 0 (256 threads) polls all flags (relaxed sc1 loads, no cache ops)
  //  - block 0 publishes go-word; everyone polls it read-only
  //  - ONE acquire fence (inv) per block on departure
  auto gbar = [&](void){
    __syncthreads();                   // all block stores drained (vmcnt 0 per wave)
    epoch++;
    if (tid==0){
      __builtin_amdgcn_fence(__ATOMIC_RELEASE, "agent");   // wbl2: push dirty lines to L3
      __hip_atomic_store(&ctrl[64 + blk*32], epoch, __ATOMIC_RELAXED, __HIP_MEMORY_SCOPE_AGENT);
    }
    if (blk==0){
      if (tid < 256){
        while (__hip_atomic_load(&ctrl[64 + tid*32], __ATOMIC_RELAXED, __HIP_MEMORY_SCOPE_AGENT) < epoch)
          __builtin_amdgcn_s_sleep(8);
      }
      __syncthreads();
      if (tid==0)
        __hip_atomic_store(&ctrl[0], epoch, __ATOMIC_RELAXED, __HIP_MEMORY_SCOPE_AGENT);
    }
    if (tid==0){
      while (__hip_atomic_load(&ctrl[0], __ATOMIC_RELAXED, __HIP_MEMORY_SCOPE_AGENT) < epoch)
        __builtin_amdgcn_s_sleep(8);
      __builtin_amdgcn_fence(__ATOMIC_ACQUIRE, "agent");   // inv: L1/L2 invalidate (once per phase)
    }
    __syncthreads();
  };

  for (int t=0; t<128; ++t){
    // ============ P1: A=pri0(h), B=pos0(h)+penc, G=h@Whh^T ============
    {
      const int bm = blk>>4, bn = blk&15;
      const int m0 = bm<<6;
      const int wm = wid&3, wh = wid>>2;
      float4_ acc[5];
      #pragma unroll
      for (int j=0;j<5;j++) acc[j]=(float4_)(0.f);
      auto stage = [&](int kf){
        for (int s=tid; s<896; s+=512){
          const int f = s>>6, l = s&63;
          short8 v;
          if (f<4) v = ldA(hbf, 512, m0 + (f<<4), kf<<5, l);
          else     v = ldB(W1cat, bn*10 + (f-4), kf, 16, l);
          *(short8*)(&sm.stg[kf&1][(f<<9) + (l<<3)]) = v;
        }
      };
      stage(0);
      for (int kf=0; kf<16; ++kf){
        __syncthreads();
        if (kf<15) stage(kf+1);
        const short* bufp = sm.stg[kf&1];
        short8 a = *(const short8*)(bufp + (wm<<9) + (lane<<3));
        #pragma unroll
        for (int j=0;j<5;j++){
          short8 b = *(const short8*)(bufp + ((4 + wh*5 + j)<<9) + (lane<<3));
          acc[j] = mfma16(a,b,acc[j]);
        }
      }
      const int mrow = m0 + (wm<<4) + ((lane>>4)<<2);
      #pragma unroll
      for (int j=0;j<5;j++){
        const int nfl = wh*5 + j;
        const int c0 = bn*160 + (nfl<<4);
        const int c  = c0 + (lane&15);
        if (c0 < 512){
          const float bs = pri_b0[c];
          #pragma unroll
          for (int e=0;e<4;e++)
            Abuf[(size_t)(mrow+e)*512 + c] = f2b(elu_(acc[j][e] + bs));
        } else if (c0 < 1024){
          const float bs = pos_b0[c-512];
          #pragma unroll
          for (int e=0;e<4;e++){
            float v = acc[j][e] + bs + b2f(penc[((size_t)t*1024 + (mrow+e))*512 + (c-512)]);
            Bbuf[(size_t)(mrow+e)*512 + (c-512)] = f2b(elu_(v));
          }
        } else {
          const float bs = bhh[c-1024];
          float4_ g;
          #pragma unroll
          for (int e=0;e<4;e++) g[e] = acc[j][e] + bs;
          const int mf = (m0>>4) + wm;
          const int nf = (c0-1024)>>4;
          *(float4_*)(Gfrag + (((size_t)mf*96 + nf)<<8) + (lane<<2)) = g;
        }
      }
    }
    gbar();
    // ============ P2: C=pri1(A), D=pos1(B) ============
    {
      const int bm = blk>>4, bn = blk&15;
      const int m0 = bm<<6;
      const int wm = wid&3, wn = wid>>2;
      const short* src = (bn<8)? Abuf : Bbuf;
      const short* Wsz = (bn<8)? priW1 : posW1;
      const float* bb  = (bn<8)? pri_b1 : pos_b1;
      short* dst = (bn<8)? Cbuf : Dbuf;
      const int nfb = (bn&7)<<2;
      float4_ acc[2];
      acc[0]=(float4_)(0.f); acc[1]=(float4_)(0.f);
      auto stage = [&](int kf){
        const int f = tid>>6, l = tid&63;
        short8 v;
        if (f<4) v = ldA(src, 512, m0+(f<<4), kf<<5, l);
        else     v = ldB(Wsz, nfb + (f-4), kf, 16, l);
        *(short8*)(&sm.stg[kf&1][(f<<9)+(l<<3)]) = v;
      };
      stage(0);
      for (int kf=0;kf<16;++kf){
        __syncthreads();
        if (kf<15) stage(kf+1);
        const short* bufp = sm.stg[kf&1];
        short8 a = *(const short8*)(bufp + (wm<<9) + (lane<<3));
        #pragma unroll
        for (int j=0;j<2;j++){
          short8 b = *(const short8*)(bufp + ((4 + (wn<<1) + j)<<9) + (lane<<3));
          acc[j] = mfma16(a,b,acc[j]);
        }
      }
      const int mrow = m0 + (wm<<4) + ((lane>>4)<<2);
      #pragma unroll
      for (int j=0;j<2;j++){
        const int cl = ((nfb + (wn<<1) + j)<<4) + (lane&15);
        const float bs = bb[cl];
        #pragma unroll
        for (int e=0;e<4;e++)
          dst[(size_t)(mrow+e)*512 + cl] = f2b(elu_(acc[j][e] + bs));
      }
    }
    gbar();
    // ============ P3: tail (64 blocks x 16 rows) ============
    if (blk < 64){
      const int m0 = blk<<4;
      {
        const int isF = wid>>2, nf2 = (wid&3)<<1;
        const short* src = isF? Dbuf : Cbuf;
        const short* Wsz = isF? posW2 : priW2;
        const float* bb  = isF? pos_b2 : pri_b2;
        float4_ acc[2];
        acc[0]=(float4_)(0.f); acc[1]=(float4_)(0.f);
        for (int kf=0;kf<16;++kf){
          short8 a = ldA(src, 512, m0, kf<<5, lane);
          #pragma unroll
          for (int j=0;j<2;j++)
            acc[j] = mfma16(a, ldB(Wsz, nf2+j, kf, 16, lane), acc[j]);
        }
        const int r0 = (lane>>4)<<2;
        #pragma unroll
        for (int j=0;j<2;j++){
          const int cl = ((nf2+j)<<4) + (lane&15);
          const float bs = bb[cl];
          #pragma unroll
          for (int e=0;e<4;e++)
            sm.p3.ef[r0+e][isF*128 + cl] = acc[j][e] + bs;
        }
      }
      __syncthreads();
      {
        const int row = tid>>5, q = tid&31;
        const int b_ = m0 + row;
        float kl2 = 0.f;
        #pragma unroll
        for (int d=0; d<2; ++d){
          const int j = (q<<1) + d;
          const float mp = sm.p3.ef[row][j],     lp = sm.p3.ef[row][64+j];
          const float mq = sm.p3.ef[row][128+j], lq = sm.p3.ef[row][192+j];
          const float ev = eps[((size_t)b_*128 + t)*64 + j];
          const float zv = mq + __expf(lq)*ev;
          const short zb = f2b(zv);
          sm.p3.z[row][j] = zb;
          zall[((size_t)t*1024 + b_)*64 + j] = zb;
          out_mu[((size_t)b_*128 + t)*64 + j] = mq;
          const float dd = mq-mp;
          kl2 += lp - lq + (__expf(2.f*lq) + dd*dd)/(2.f*__expf(2.f*lp)) - 0.5f;
        }
        #pragma unroll
        for (int off=16; off; off>>=1) kl2 += __shfl_xor(kl2, off, 32);
        if (q==0) out_kls[(size_t)b_*128 + t] = kl2;
      }
      __syncthreads();
      {
        short8 za0 = *(const short8*)(&sm.p3.z[lane&15][((lane>>4)<<3)]);
        short8 za1 = *(const short8*)(&sm.p3.z[lane&15][32 + ((lane>>4)<<3)]);
        float4_ gacc[3][4];
        #pragma unroll
        for (int s=0;s<3;s++)
          #pragma unroll
          for (int j4=0;j4<4;j4++){
            gacc[s][j4] = (float4_)(0.f);
            const int nf = s*32 + (wid<<2) + j4;
            gacc[s][j4] = mfma16(za0, ldB(Wih, nf, 0, 2, lane), gacc[s][j4]);
            gacc[s][j4] = mfma16(za1, ldB(Wih, nf, 1, 2, lane), gacc[s][j4]);
          }
        const int mf = blk;
        #pragma unroll
        for (int j4=0;j4<4;j4++){
          const int ccol = (wid<<6) + (j4<<4) + (lane&15);
          const float br = bih[ccol], bz = bih[512+ccol], bn_ = bih[1024+ccol];
          const int nfh = (wid<<2) + j4;
          float4_ gr = *(const float4_*)(Gfrag + (((size_t)mf*96 + nfh)<<8) + (lane<<2));
          float4_ gz = *(const float4_*)(Gfrag + (((size_t)mf*96 + 32 + nfh)<<8) + (lane<<2));
          float4_ gn = *(const float4_*)(Gfrag + (((size_t)mf*96 + 64 + nfh)<<8) + (lane<<2));
          float* hp = hfrag + (((size_t)mf*32 + nfh)<<8) + (lane<<2);
          float4_ hold = *(const float4_*)hp;
          float4_ hnew;
          #pragma unroll
          for (int e=0;e<4;e++){
            const float r  = sigm_(gacc[0][j4][e] + br + gr[e]);
            const float zg = sigm_(gacc[1][j4][e] + bz + gz[e]);
            const float nn = tanh_(gacc[2][j4][e] + bn_ + r*gn[e]);
            hnew[e] = (1.f-zg)*nn + zg*hold[e];
          }
          *(float4_*)hp = hnew;
          const int mrow = m0 + ((lane>>4)<<2);
          #pragma unroll
          for (int e=0;e<4;e++)
            hbf[(size_t)(mrow+e)*512 + ccol] = f2b(hnew[e]);
        }
      }
    }
    gbar();
  }
}

// ---------------- fused decoder: z -> recons ----------------
__global__ __launch_bounds__(512,1) void k_dec(
    const short* __restrict__ zall,
    const short* __restrict__ w0, const short* __restrict__ w1, const short* __restrict__ w2,
    const float* __restrict__ b0v, const float* __restrict__ b1v, const float* __restrict__ b2v,
    float* __restrict__ rec)
{
  __shared__ short zf[64][72];
  __shared__ short x1[64][520];
  const int tid=threadIdx.x, lane=tid&63, wid=tid>>6;
  const int wm=wid&1, wn=wid>>1;
  const size_t m0 = (size_t)blockIdx.x<<6;
  {
    const int row = tid>>3, ch = (tid&7)<<3;
    *(short8*)(&zf[row][ch]) = *(const short8*)(zall + (m0+row)*64 + ch);
  }
  __syncthreads();
  float4_ acc[2][8];
  // L1 (K=64)
  #pragma unroll
  for (int am=0;am<2;am++)
    #pragma unroll
    for (int nj=0;nj<8;nj++) acc[am][nj]=(float4_)(0.f);
  for (int kf=0;kf<2;++kf){
    short8 a0 = *(const short8*)(&zf[(wm<<5)+(lane&15)][(kf<<5)+((lane>>4)<<3)]);
    short8 a1 = *(const short8*)(&zf[(wm<<5)+16+(lane&15)][(kf<<5)+((lane>>4)<<3)]);
    #pragma unroll
    for (int nj=0;nj<8;nj++){
      short8 b = ldB(w0, (wn<<3)+nj, kf, 2, lane);
      acc[0][nj] = mfma16(a0,b,acc[0][nj]);
      acc[1][nj] = mfma16(a1,b,acc[1][nj]);
    }
  }
  #pragma unroll
  for (int am=0;am<2;am++)
    #pragma unroll
    for (int nj=0;nj<8;nj++){
      const int col=(wn<<7)+(nj<<4)+(lane&15);
      const float bs=b0v[col];
      #pragma unroll
      for (int e=0;e<4;e++)
        x1[(wm<<5)+(am<<4)+((lane>>4)<<2)+e][col]=f2b(elu_(acc[am][nj][e]+bs));
    }
  __syncthreads();
  // L2 (K=512)
  #pragma unroll
  for (int am=0;am<2;am++)
    #pragma unroll
    for (int nj=0;nj<8;nj++) acc[am][nj]=(float4_)(0.f);
  for (int kf=0;kf<16;++kf){
    short8 a0 = *(const short8*)(&x1[(wm<<5)+(lane&15)][(kf<<5)+((lane>>4)<<3)]);
    short8 a1 = *(const short8*)(&x1[(wm<<5)+16+(lane&15)][(kf<<5)+((lane>>4)<<3)]);
    #pragma unroll
    for (int nj=0;nj<8;nj++){
      short8 b = ldB(w1, (wn<<3)+nj, kf, 16, lane);
      acc[0][nj] = mfma16(a0,b,acc[0][nj]);
      acc[1][nj] = mfma16(a1,b,acc[1][nj]);
    }
  }
  __syncthreads();
  #pragma unroll
  for (int am=0;am<2;am++)
    #pragma unroll
    for (int nj=0;nj<8;nj++){
      const int col=(wn<<7)+(nj<<4)+(lane&15);
      const float bs=b1v[col];
      #pragma unroll
      for (int e=0;e<4;e++)
        x1[(wm<<5)+(am<<4)+((lane>>4)<<2)+e][col]=f2b(elu_(acc[am][nj][e]+bs));
    }
  __syncthreads();
  // L3 (K=512, N=256) -> rec with (t,b)->(b,t) permute
  float4_ a3[2][4];
  #pragma unroll
  for (int am=0;am<2;am++)
    #pragma unroll
    for (int nj=0;nj<4;nj++) a3[am][nj]=(float4_)(0.f);
  for (int kf=0;kf<16;++kf){
    short8 a0 = *(const short8*)(&x1[(wm<<5)+(lane&15)][(kf<<5)+((lane>>4)<<3)]);
    short8 a1 = *(const short8*)(&x1[(wm<<5)+16+(lane&15)][(kf<<5)+((lane>>4)<<3)]);
    #pragma unroll
    for (int nj=0;nj<4;nj++){
      short8 b = ldB(w2, (wn<<2)+nj, kf, 16, lane);
      a3[0][nj] = mfma16(a0,b,a3[0][nj]);
      a3[1][nj] = mfma16(a1,b,a3[1][nj]);
    }
  }
  #pragma unroll
  for (int am=0;am<2;am++)
    #pragma unroll
    for (int nj=0;nj<4;nj++){
      const int col=(wn<<6)+(nj<<4)+(lane&15);
      const float bs=b2v[col];
      #pragma unroll
      for (int e=0;e<4;e++){
        const int row=(wm<<5)+(am<<4)+((lane>>4)<<2)+e;
        const size_t r = m0+row;
        rec[(((r&1023)<<7) + (r>>10))*256 + col] = a3[am][nj][e]+bs;
      }
    }
}

extern "C" void kernel_launch(void* const* d_in, const int* in_sizes, int n_in,
                              void* d_out, int out_size, void* d_ws, size_t ws_size,
                              hipStream_t stream)
{
  (void)in_sizes; (void)n_in; (void)out_size; (void)ws_size;
  const float* obs = (const float*)d_in[0];
  const float* eps = (const float*)d_in[1];
  const float* eW0 = (const float*)d_in[2];
  const float* eb0 = (const float*)d_in[3];
  const float* eW1 = (const float*)d_in[4];
  const float* eb1 = (const float*)d_in[5];
  const float* eW2 = (const float*)d_in[6];
  const float* eb2 = (const float*)d_in[7];
  const float* pW0 = (const float*)d_in[8];
  const float* pb0 = (const float*)d_in[9];
  const float* pW1 = (const float*)d_in[10];
  const float* pb1 = (const float*)d_in[11];
  const float* pW2 = (const float*)d_in[12];
  const float* pb2 = (const float*)d_in[13];
  const float* qW0 = (const float*)d_in[14];
  const float* qb0 = (const float*)d_in[15];
  const float* qW1 = (const float*)d_in[16];
  const float* qb1 = (const float*)d_in[17];
  const float* qW2 = (const float*)d_in[18];
  const float* qb2 = (const float*)d_in[19];
  const float* dW0 = (const float*)d_in[20];
  const float* db0 = (const float*)d_in[21];
  const float* dW1 = (const float*)d_in[22];
  const float* db1 = (const float*)d_in[23];
  const float* dW2 = (const float*)d_in[24];
  const float* db2 = (const float*)d_in[25];
  const float* gWih = (const float*)d_in[26];
  const float* gbih = (const float*)d_in[27];
  const float* gWhh = (const float*)d_in[28];
  const float* gbhh = (const float*)d_in[29];

  float* out_rec = (float*)d_out;
  float* out_kls = out_rec + (size_t)1024*128*256;
  float* out_mu  = out_kls + (size_t)1024*128;

  char* w = (char*)d_ws;
  auto alloc = [&](size_t bytes)->char*{ char* p=w; w += (bytes+255)&~(size_t)255; return p; };
  unsigned* ctrl = (unsigned*)alloc(36864);
  short* W1cat  = (short*)alloc((size_t)1310720*2);
  short* priW1s = (short*)alloc((size_t)262144*2);
  short* posW1s = (short*)alloc((size_t)262144*2);
  short* priW2s = (short*)alloc((size_t)65536*2);
  short* posW2s = (short*)alloc((size_t)65536*2);
  short* Wihs   = (short*)alloc((size_t)98304*2);
  short* encW0s = (short*)alloc((size_t)131072*2);
  short* encW1s = (short*)alloc((size_t)262144*2);
  short* wces   = (short*)alloc((size_t)262144*2);
  short* decW0s = (short*)alloc((size_t)32768*2);
  short* decW1s = (short*)alloc((size_t)262144*2);
  short* decW2s = (short*)alloc((size_t)131072*2);
  float* wce_rm = (float*)alloc((size_t)262144*4);
  float* bce    = (float*)alloc(512*4);
  float* hfrag  = (float*)alloc((size_t)524288*4);
  short* hbf    = (short*)alloc((size_t)524288*2);
  short* Abuf   = (short*)alloc((size_t)524288*2);
  short* Bbuf   = (short*)alloc((size_t)524288*2);
  short* Cbuf   = (short*)alloc((size_t)524288*2);
  short* Dbuf   = (short*)alloc((size_t)524288*2);
  float* Gfrag  = (float*)alloc((size_t)1572864*4);
  short* zall   = (short*)alloc((size_t)8388608*2);
  short* penc   = (short*)alloc((size_t)67108864*2);

  k_init<<<2048,256,0,stream>>>(ctrl, hfrag, hbf);
  k_swz<<<dim3(16,32),64,0,stream>>>(pW0,  W1cat, 512, 0,  0, 16);
  k_swz<<<dim3(16,32),64,0,stream>>>(qW0,  W1cat, 1024,0, 32, 16);
  k_swz<<<dim3(16,96),64,0,stream>>>(gWhh, W1cat, 512, 0, 64, 16);
  k_swz<<<dim3(16,32),64,0,stream>>>(pW1, priW1s, 512,0,0,16);
  k_swz<<<dim3(16,32),64,0,stream>>>(qW1, posW1s, 512,0,0,16);
  k_swz<<<dim3(16,8 ),64,0,stream>>>(pW2, priW2s, 512,0,0,16);
  k_swz<<<dim3(16,8 ),64,0,stream>>>(qW2, posW2s, 512,0,0,16);
  k_swz<<<dim3(2,96 ),64,0,stream>>>(gWih, Wihs, 64,0,0,2);
  k_swz<<<dim3(8,32 ),64,0,stream>>>(eW0, encW0s, 256,0,0,8);
  k_swz<<<dim3(16,32),64,0,stream>>>(eW1, encW1s, 512,0,0,16);
  k_swz<<<dim3(2,32 ),64,0,stream>>>(dW0, decW0s, 64,0,0,2);
  k_swz<<<dim3(16,32),64,0,stream>>>(dW1, decW1s, 512,0,0,16);
  k_swz<<<dim3(16,16),64,0,stream>>>(dW2, decW2s, 512,0,0,16);
  k_wce<<<dim3(32,32),256,0,stream>>>(qW0, eW2, wce_rm);
  k_bce<<<1,512,0,stream>>>(qW0, eb2, bce);
  k_swz<<<dim3(16,32),64,0,stream>>>(wce_rm, wces, 512,0,0,16);
  k_enc<<<2048,512,0,stream>>>(obs, encW0s, encW1s, wces, eb0, eb1, bce, penc);
  k_scan<<<GRIDN,512,0,stream>>>(eps, penc, W1cat, priW1s, posW1s, priW2s, posW2s, Wihs,
      pb0, qb0, gbhh, pb1, qb1, pb2, qb2, gbih,
      hfrag, hbf, Abuf, Bbuf, Cbuf, Dbuf, Gfrag, zall, out_kls, out_mu, ctrl);
  k_dec<<<2048,512,0,stream>>>(zall, decW0s, decW1s, decW2s, db0, db1, db2, out_rec);
}